// Round 15
// baseline (89.956 us; speedup 1.0000x reference)
//
#include <hip/hip_runtime.h>
#include <math.h>

#define BATCH 4
#define SEQ   1024
#define HID   512
#define NHEAD 8

typedef unsigned short u16;
typedef unsigned int   u32;
typedef short  short8 __attribute__((ext_vector_type(8)));
typedef float  f32x4  __attribute__((ext_vector_type(4)));

__device__ __forceinline__ u16 f2bf(float x) {
  u32 u = __builtin_bit_cast(u32, x);
  u32 r = (u + 0x7FFFu + ((u >> 16) & 1u)) >> 16;
  return (u16)r;
}
__device__ __forceinline__ float bf2f(u16 h) {
  u32 u = ((u32)h) << 16;
  return __builtin_bit_cast(float, u);
}

// ---------------- fused prologue: bf16 converts + 5 weight transposes --------
__global__ __launch_bounds__(256)
void prep(const float* __restrict__ x, const float* __restrict__ pe,
          const float* __restrict__ w0, const float* __restrict__ w1,
          const float* __restrict__ w2, const float* __restrict__ w3,
          const float* __restrict__ w4,
          u16* __restrict__ xb, u16* __restrict__ peb, u16* __restrict__ wt) {
  __shared__ float t[32][33];
  const int bid = blockIdx.x, tid = threadIdx.x;
  if (bid < 3072) {
    int i = bid * 256 + tid;
    const float* s;
    u16* d;
    if (i < 524288) {
      s = x; d = xb;
    } else {
      i -= 524288;
      if (i >= 262016) return;
      s = pe; d = peb;
    }
    float4 v = *(const float4*)&s[(size_t)i * 4];
    ushort4 o;
    o.x = f2bf(v.x); o.y = f2bf(v.y); o.z = f2bf(v.z); o.w = f2bf(v.w);
    *(ushort4*)&d[(size_t)i * 4] = o;
  } else {
    const int b2 = bid - 3072;
    const int z = b2 >> 8;
    const int rem = b2 & 255;
    const int k0 = (rem & 15) * 32, n0 = (rem >> 4) * 32;
    const float* src = (z == 0) ? w0 : (z == 1) ? w1 : (z == 2) ? w2
                                                     : (z == 3) ? w3 : w4;
    u16* dst = wt + (size_t)z * 512 * 512;
    const int tx = tid & 31, ty = tid >> 5;
#pragma unroll
    for (int r = 0; r < 4; ++r)
      t[ty + 8 * r][tx] = src[(size_t)(k0 + ty + 8 * r) * 512 + n0 + tx];
    __syncthreads();
#pragma unroll
    for (int r = 0; r < 4; ++r)
      dst[(size_t)(n0 + ty + 8 * r) * 512 + k0 + tx] = f2bf(t[tx][ty + 8 * r]);
  }
}

// ---------------- MFMA GEMM core (serial reg staging — verified) -------------
template <int MF, int NF>
__device__ __forceinline__ void gemm_core(const u16* __restrict__ A,
                                          const u16* __restrict__ Bt,
                                          int m0, int n0, u16* As, u16* Bs,
                                          f32x4 (&acc)[MF][NF]) {
  const int tid = threadIdx.x;
  const int wid = tid >> 6, lane = tid & 63;
  const int lr = lane & 15, lg = lane >> 4;
  const int wm = wid >> 1, wn = wid & 1;
  const int srow = tid >> 3, sc = tid & 7;
#pragma unroll
  for (int i = 0; i < MF; ++i)
#pragma unroll
    for (int j = 0; j < NF; ++j) acc[i][j] = (f32x4)0.f;

  for (int kt = 0; kt < 8; ++kt) {
    const int k0 = kt * 64;
    short8 la[MF], lb[NF];
#pragma unroll
    for (int r = 0; r < MF; ++r)
      la[r] = *(const short8*)&A[(size_t)(m0 + srow + 32 * r) * 512 + k0 + sc * 8];
#pragma unroll
    for (int r = 0; r < NF; ++r)
      lb[r] = *(const short8*)&Bt[(size_t)(n0 + srow + 32 * r) * 512 + k0 + sc * 8];
    __syncthreads();
#pragma unroll
    for (int r = 0; r < MF; ++r) {
      int row = srow + 32 * r;
      *(short8*)&As[row * 64 + ((sc ^ (row & 7)) * 8)] = la[r];
    }
#pragma unroll
    for (int r = 0; r < NF; ++r) {
      int row = srow + 32 * r;
      *(short8*)&Bs[row * 64 + ((sc ^ (row & 7)) * 8)] = lb[r];
    }
    __syncthreads();
#pragma unroll
    for (int kc = 0; kc < 2; ++kc) {
      const int ch = kc * 4 + lg;
      short8 af[MF], bfr[NF];
#pragma unroll
      for (int mt = 0; mt < MF; ++mt) {
        int row = wm * (MF * 16) + mt * 16 + lr;
        af[mt] = *(const short8*)&As[row * 64 + ((ch ^ (row & 7)) * 8)];
      }
#pragma unroll
      for (int nt = 0; nt < NF; ++nt) {
        int row = wn * (NF * 16) + nt * 16 + lr;
        bfr[nt] = *(const short8*)&Bs[row * 64 + ((ch ^ (row & 7)) * 8)];
      }
#pragma unroll
      for (int mt = 0; mt < MF; ++mt)
#pragma unroll
        for (int nt = 0; nt < NF; ++nt)
          acc[mt][nt] = __builtin_amdgcn_mfma_f32_16x16x32_bf16(
              af[mt], bfr[nt], acc[mt][nt], 0, 0, 0);
    }
  }
}

// ---------------- fused Q/K/V/P projection GEMM (z = 0..3) ------------------
__global__ __launch_bounds__(256)
void gemm_qkvp(const u16* __restrict__ xbf, const u16* __restrict__ pebf,
               const u16* __restrict__ wt,
               const float* __restrict__ bq, const float* __restrict__ bk,
               const float* __restrict__ bv, const float* __restrict__ bp,
               u16* __restrict__ qq, u16* __restrict__ kk,
               u16* __restrict__ vt, u16* __restrict__ pp) {
  __shared__ __align__(16) u16 As[128 * 64];
  __shared__ __align__(16) u16 Bs[128 * 64];
  const int z = blockIdx.z;
  if (z == 3 && blockIdx.y >= 16) return;
  const u16* A = (z == 3) ? pebf : xbf;
  const u16* Bt = wt + (size_t)z * 512 * 512;
  const float* bias = (z == 0) ? bq : (z == 1) ? bk : (z == 2) ? bv : bp;
  const int m0 = blockIdx.y * 128, n0 = blockIdx.x * 128;

  f32x4 acc[4][4];
  gemm_core<4, 4>(A, Bt, m0, n0, As, Bs, acc);

  const int tid = threadIdx.x, wid = tid >> 6, lane = tid & 63;
  const int lr = lane & 15, lg = lane >> 4, wm = wid >> 1, wn = wid & 1;
#pragma unroll
  for (int mt = 0; mt < 4; ++mt)
#pragma unroll
    for (int nt = 0; nt < 4; ++nt) {
      const int col = n0 + wn * 64 + nt * 16 + lr;
      const int rb = m0 + wm * 64 + mt * 16 + lg * 4;
      const float bcol = bias[col];
      if (z == 0) {
#pragma unroll
        for (int q = 0; q < 4; ++q)
          qq[(size_t)(rb + q) * 512 + col] = f2bf(acc[mt][nt][q] + bcol);
      } else if (z == 1) {
#pragma unroll
        for (int q = 0; q < 4; ++q)
          kk[(size_t)(rb + q) * 512 + col] = f2bf(acc[mt][nt][q] + bcol);
      } else if (z == 2) {
        ushort4 pk;
        pk.x = f2bf(acc[mt][nt][0] + bcol);
        pk.y = f2bf(acc[mt][nt][1] + bcol);
        pk.z = f2bf(acc[mt][nt][2] + bcol);
        pk.w = f2bf(acc[mt][nt][3] + bcol);
        int bb = rb >> 10, tl = rb & 1023;
        *(ushort4*)&vt[(size_t)((bb * 8 + (col >> 6)) * 64 + (col & 63)) * 1024 + tl] = pk;
      } else {
#pragma unroll
        for (int q = 0; q < 4; ++q)
          if (rb + q < 2047)
            pp[(size_t)(rb + q) * 512 + col] = f2bf(acc[mt][nt][q] + bcol);
      }
    }
}

// ---------------- output projection: out = ao @ Wo^T + bo (f32) -------------
__global__ __launch_bounds__(256)
void gemm_wo(const u16* __restrict__ ao, const u16* __restrict__ wt,
             const float* __restrict__ bo, float* __restrict__ out) {
  __shared__ __align__(16) u16 As[64 * 64];
  __shared__ __align__(16) u16 Bs[64 * 64];
  const int m0 = blockIdx.y * 64, n0 = blockIdx.x * 64;
  f32x4 acc[2][2];
  gemm_core<2, 2>(ao, wt + (size_t)4 * 512 * 512, m0, n0, As, Bs, acc);
  const int tid = threadIdx.x, wid = tid >> 6, lane = tid & 63;
  const int lr = lane & 15, lg = lane >> 4, wm = wid >> 1, wn = wid & 1;
#pragma unroll
  for (int mt = 0; mt < 2; ++mt)
#pragma unroll
    for (int nt = 0; nt < 2; ++nt) {
      const int col = n0 + wn * 32 + nt * 16 + lr;
      const int rb = m0 + wm * 32 + mt * 16 + lg * 4;
      const float bcol = bo[col];
#pragma unroll
      for (int q = 0; q < 4; ++q)
        out[(size_t)(rb + q) * 512 + col] = acc[mt][nt][q] + bcol;
    }
}

// ---------------- flash rel-pos attention: phase-batched f0/f1 chains --------
// Separate bf16 Bds/Es buffers per f so the two row-frag chains interleave
// (was: serial f-loop through one shared buffer => pipes ran serially).
__global__ __launch_bounds__(512)
void attn_mfma(const u16* __restrict__ qP, const float* __restrict__ pbu,
               const float* __restrict__ pbv,
               const u16* __restrict__ kP, const u16* __restrict__ vtP,
               const u16* __restrict__ pP, u16* __restrict__ ao) {
  // u16 layout: Ks[2]@0 (16KB), Vs[2]@8192 (16KB), Ps@16384 (32KB),
  // Wb@32768: per-wave 2816 u16 (two 1408-u16 f-halves, Bds bf16 + Es overlay)
  __shared__ __align__(16) u16 SM[55296];
  u16* Ps = SM + 16384;

  const int tid = threadIdx.x;
  const int wid = tid >> 6, lane = tid & 63;
  const int lr = lane & 15, lg = lane >> 4;
  const int grp = wid >> 2, wq = wid & 3;
  const int t0 = blockIdx.x * 128, h = blockIdx.y, b = blockIdx.z;
  const int base0 = 896 - t0;

  u16* Ksg = SM + grp * 4096;
  u16* Vsg = SM + 8192 + grp * 4096;
  u16* wbh = SM + 32768 + wid * 2816;  // [f*1408 + ...]

  // Q fragments from single q tensor + in-register u/v bias add
  short8 aqu[2][2], aqv[2][2];
#pragma unroll
  for (int kc = 0; kc < 2; ++kc) {
    float4 u0 = *(const float4*)&pbu[h * 64 + kc * 32 + lg * 8];
    float4 u1 = *(const float4*)&pbu[h * 64 + kc * 32 + lg * 8 + 4];
    float4 v0 = *(const float4*)&pbv[h * 64 + kc * 32 + lg * 8];
    float4 v1 = *(const float4*)&pbv[h * 64 + kc * 32 + lg * 8 + 4];
    float ub[8] = {u0.x, u0.y, u0.z, u0.w, u1.x, u1.y, u1.z, u1.w};
    float vb[8] = {v0.x, v0.y, v0.z, v0.w, v1.x, v1.y, v1.z, v1.w};
#pragma unroll
    for (int f = 0; f < 2; ++f) {
      size_t g = (size_t)(b * SEQ + t0 + 32 * wq + 16 * f + lr) * 512 + h * 64 +
                 kc * 32 + lg * 8;
      short8 q8 = *(const short8*)&qP[g];
#pragma unroll
      for (int i = 0; i < 8; ++i) {
        float qf = bf2f((u16)q8[i]);
        aqu[f][kc][i] = (short)f2bf(qf + ub[i]);
        aqv[f][kc][i] = (short)f2bf(qf + vb[i]);
      }
    }
  }
  short8 ones;
#pragma unroll
  for (int i = 0; i < 8; ++i) ones[i] = (short)0x3F80;

  float mrun[2] = {-1e30f, -1e30f};
  f32x4 cL[2], cO[2][4];
#pragma unroll
  for (int f = 0; f < 2; ++f) {
    cL[f] = (f32x4)0.f;
#pragma unroll
    for (int nt = 0; nt < 4; ++nt) cO[f][nt] = (f32x4)0.f;
  }

#pragma unroll
  for (int r = 0; r < 2; ++r) {
    int idx = tid + 512 * r;
    int row = idx >> 3, sc = idx & 7;
    short8 lk = *(const short8*)&kP[(size_t)(b * SEQ + row) * 512 + h * 64 + sc * 8];
    short8 lv = *(const short8*)&vtP[(size_t)((b * 8 + h) * 64 + (row & 63)) * 1024 +
                                     (row >> 6) * 64 + sc * 8];
    *(short8*)&SM[(row >> 6) * 4096 + (row & 63) * 64 + ((sc ^ (row & 7)) * 8)] = lk;
    *(short8*)&SM[8192 + (row >> 6) * 4096 + (row & 63) * 64 + ((sc ^ (row & 7)) * 8)] = lv;
  }
#pragma unroll
  for (int r = 0; r < 4; ++r) {
    int idx = tid + 512 * r;
    int prow = idx >> 3, sc = idx & 7;
    short8 lp = *(const short8*)&pP[(size_t)(base0 + prow) * 512 + h * 64 + sc * 8];
    *(short8*)&Ps[prow * 64 + ((sc ^ (prow & 7)) * 8)] = lp;
  }
  __syncthreads();

  for (int s = 0; s < 8; ++s) {
    // ---- T14: issue next superstep's global loads early ----
    short8 nk[2], nv[2], np[2];
    if (s < 7) {
      const int jn = 128 * (s + 1);
#pragma unroll
      for (int r = 0; r < 2; ++r) {
        int idx = tid + 512 * r;
        int row = idx >> 3, sc = idx & 7;
        nk[r] = *(const short8*)&kP[(size_t)(b * SEQ + jn + row) * 512 + h * 64 + sc * 8];
        nv[r] = *(const short8*)&vtP[(size_t)((b * 8 + h) * 64 + (row & 63)) * 1024 +
                                     jn + (row >> 6) * 64 + sc * 8];
        np[r] = *(const short8*)&pP[(size_t)(base0 + 256 + 128 * s + row) * 512 +
                                    h * 64 + sc * 8];
      }
    }

    // ---- phase 1: QK^T MFMAs (both f share K frags) ----
    f32x4 cKT[2][4];
#pragma unroll
    for (int f = 0; f < 2; ++f)
#pragma unroll
      for (int nt = 0; nt < 4; ++nt) cKT[f][nt] = (f32x4)0.f;
    __builtin_amdgcn_s_setprio(1);
#pragma unroll
    for (int kc = 0; kc < 2; ++kc) {
      const int ch = kc * 4 + lg;
#pragma unroll
      for (int nt = 0; nt < 4; ++nt) {
        int krow = nt * 16 + lr;
        short8 bk = *(const short8*)&Ksg[krow * 64 + ((ch ^ (krow & 7)) * 8)];
        cKT[0][nt] = __builtin_amdgcn_mfma_f32_16x16x32_bf16(bk, aqu[0][kc], cKT[0][nt], 0, 0, 0);
        cKT[1][nt] = __builtin_amdgcn_mfma_f32_16x16x32_bf16(bk, aqu[1][kc], cKT[1][nt], 0, 0, 0);
      }
    }
    __builtin_amdgcn_s_setprio(0);

    // ---- hoist V fragments ----
    short8 bvr[2][4];
#pragma unroll
    for (int kc = 0; kc < 2; ++kc) {
      const int ch = kc * 4 + lg;
#pragma unroll
      for (int nt = 0; nt < 4; ++nt) {
        int vr = nt * 16 + lr;
        bvr[kc][nt] = *(const short8*)&Vsg[vr * 64 + ((ch ^ (vr & 7)) * 8)];
      }
    }

    // ---- phase 2: P MFMAs, BOTH f (f1 reuses f0's frags) ----
    const int poff0 = 112 - 32 * wq + 64 * grp + 128 * s;
    f32x4 cPT[2][5];
#pragma unroll
    for (int f = 0; f < 2; ++f)
#pragma unroll
      for (int i = 0; i < 5; ++i) cPT[f][i] = (f32x4)0.f;
    __builtin_amdgcn_s_setprio(1);
#pragma unroll
    for (int kc = 0; kc < 2; ++kc) {
      const int ch = kc * 4 + lg;
      const int swz = (ch ^ (lr & 7)) * 8;
      short8 bpc[4];
#pragma unroll
      for (int pt = 0; pt < 5; ++pt) {
        int pos = (poff0 + pt * 16 + lr) & 255;
        short8 bp = *(const short8*)&Ps[pos * 64 + swz];
        if (pt < 4) bpc[pt] = bp;
        cPT[0][pt] = __builtin_amdgcn_mfma_f32_16x16x32_bf16(bp, aqv[0][kc], cPT[0][pt], 0, 0, 0);
      }
      int pos1 = (poff0 - 16 + lr) & 255;
      short8 bp1 = *(const short8*)&Ps[pos1 * 64 + swz];
      cPT[1][0] = __builtin_amdgcn_mfma_f32_16x16x32_bf16(bp1, aqv[1][kc], cPT[1][0], 0, 0, 0);
#pragma unroll
      for (int pt = 1; pt < 5; ++pt)
        cPT[1][pt] = __builtin_amdgcn_mfma_f32_16x16x32_bf16(bpc[pt - 1], aqv[1][kc], cPT[1][pt], 0, 0, 0);
    }
    __builtin_amdgcn_s_setprio(0);

    // ---- phase 3: Bds writes (bf16, separate f buffers) ----
#pragma unroll
    for (int f = 0; f < 2; ++f)
#pragma unroll
      for (int pt = 0; pt < 5; ++pt) {
        uint2 pk;
        pk.x = (u32)f2bf(cPT[f][pt][0]) | ((u32)f2bf(cPT[f][pt][1]) << 16);
        pk.y = (u32)f2bf(cPT[f][pt][2]) | ((u32)f2bf(cPT[f][pt][3]) << 16);
        *(uint2*)&wbh[f * 1408 + lr * 88 + pt * 16 + lg * 4] = pk;
      }

    // ---- phase 4: shifted reads + scores (both f) ----
    float sv[2][4][4];
#pragma unroll
    for (int f = 0; f < 2; ++f)
#pragma unroll
      for (int nt = 0; nt < 4; ++nt)
#pragma unroll
        for (int q = 0; q < 4; ++q)
          sv[f][nt][q] = 0.125f * (cKT[f][nt][q] +
              bf2f(wbh[f * 1408 + lr * 88 + 16 * nt + lg * 4 + q + 15 - lr]));

    // ---- phase 5: per-lane max + defer-max rescale (both f) ----
    float tmx[2];
#pragma unroll
    for (int f = 0; f < 2; ++f) {
      float tm = sv[f][0][0];
#pragma unroll
      for (int nt = 0; nt < 4; ++nt)
#pragma unroll
        for (int q = 0; q < 4; ++q) tm = fmaxf(tm, sv[f][nt][q]);
      tmx[f] = tm;
    }
#pragma unroll
    for (int f = 0; f < 2; ++f) {
      tmx[f] = fmaxf(tmx[f], __shfl_xor(tmx[f], 16));
      tmx[f] = fmaxf(tmx[f], __shfl_xor(tmx[f], 32));
    }
#pragma unroll
    for (int f = 0; f < 2; ++f) {
      if (__any(tmx[f] > mrun[f] + 8.f)) {
        float mnew = fmaxf(mrun[f], tmx[f]);
        float corr = __expf(mrun[f] - mnew);
        mrun[f] = mnew;
        float cc[4];
#pragma unroll
        for (int q = 0; q < 4; ++q)
          cc[q] = __shfl(corr, (lane & 48) | (lg * 4 + q));
#pragma unroll
        for (int q = 0; q < 4; ++q) {
          cL[f][q] *= cc[q];
#pragma unroll
          for (int nt = 0; nt < 4; ++nt) cO[f][nt][q] *= cc[q];
        }
      }
    }

    // ---- phase 6: exp -> bf16 -> Es (both f, separate buffers) ----
#pragma unroll
    for (int f = 0; f < 2; ++f)
#pragma unroll
      for (int nt = 0; nt < 4; ++nt) {
        float e0 = __expf(sv[f][nt][0] - mrun[f]);
        float e1 = __expf(sv[f][nt][1] - mrun[f]);
        float e2 = __expf(sv[f][nt][2] - mrun[f]);
        float e3 = __expf(sv[f][nt][3] - mrun[f]);
        uint2 pk;
        pk.x = (u32)f2bf(e0) | ((u32)f2bf(e1) << 16);
        pk.y = (u32)f2bf(e2) | ((u32)f2bf(e3) << 16);
        int g = 2 * nt + (lg >> 1);
        *(uint2*)&wbh[f * 1408 + lr * 64 + ((g ^ (lr & 7)) * 8) + (lg & 1) * 4] = pk;
      }

    // ---- phase 7: PV + denominator (both f) ----
    __builtin_amdgcn_s_setprio(1);
#pragma unroll
    for (int kc = 0; kc < 2; ++kc) {
      const int ch = kc * 4 + lg;
      short8 pa0 = *(const short8*)&wbh[0 * 1408 + lr * 64 + ((ch ^ (lr & 7)) * 8)];
      short8 pa1 = *(const short8*)&wbh[1 * 1408 + lr * 64 + ((ch ^ (lr & 7)) * 8)];
      cL[0] = __builtin_amdgcn_mfma_f32_16x16x32_bf16(pa0, ones, cL[0], 0, 0, 0);
      cL[1] = __builtin_amdgcn_mfma_f32_16x16x32_bf16(pa1, ones, cL[1], 0, 0, 0);
#pragma unroll
      for (int nt = 0; nt < 4; ++nt) {
        cO[0][nt] = __builtin_amdgcn_mfma_f32_16x16x32_bf16(pa0, bvr[kc][nt], cO[0][nt], 0, 0, 0);
        cO[1][nt] = __builtin_amdgcn_mfma_f32_16x16x32_bf16(pa1, bvr[kc][nt], cO[1][nt], 0, 0, 0);
      }
    }
    __builtin_amdgcn_s_setprio(0);

    __syncthreads();
    if (s < 7) {
#pragma unroll
      for (int r = 0; r < 2; ++r) {
        int idx = tid + 512 * r;
        int row = idx >> 3, sc = idx & 7;
        *(short8*)&SM[(row >> 6) * 4096 + (row & 63) * 64 + ((sc ^ (row & 7)) * 8)] = nk[r];
        *(short8*)&SM[8192 + (row >> 6) * 4096 + (row & 63) * 64 + ((sc ^ (row & 7)) * 8)] = nv[r];
        int pos = (128 * s + row) & 255;
        *(short8*)&Ps[pos * 64 + ((sc ^ (pos & 7)) * 8)] = np[r];
      }
    }
    __syncthreads();
  }

  float m_c[2][4];
#pragma unroll
  for (int f = 0; f < 2; ++f)
#pragma unroll
    for (int q = 0; q < 4; ++q)
      m_c[f][q] = __shfl(mrun[f], (lane & 48) | (lg * 4 + q));

  float* ob = (float*)SM;
  float* mlb = (float*)(SM + 16384);
  if (grp == 1) {
#pragma unroll
    for (int f = 0; f < 2; ++f) {
#pragma unroll
      for (int nt = 0; nt < 4; ++nt)
#pragma unroll
        for (int q = 0; q < 4; ++q)
          ob[(wq * 32 + 16 * f + 4 * lg + q) * 64 + nt * 16 + lr] = cO[f][nt][q];
      if (lr == 0) {
#pragma unroll
        for (int q = 0; q < 4; ++q) {
          int rr = wq * 32 + 16 * f + 4 * lg + q;
          mlb[rr * 2 + 0] = m_c[f][q];
          mlb[rr * 2 + 1] = cL[f][q];
        }
      }
    }
  }
  __syncthreads();
  if (grp == 0) {
#pragma unroll
    for (int f = 0; f < 2; ++f) {
      float ws0[4], ws1[4];
#pragma unroll
      for (int q = 0; q < 4; ++q) {
        int rr = wq * 32 + 16 * f + 4 * lg + q;
        float m1 = mlb[rr * 2 + 0], l1 = mlb[rr * 2 + 1];
        float M = fmaxf(m_c[f][q], m1);
        float w0 = __expf(m_c[f][q] - M), w1 = __expf(m1 - M);
        float inv = 1.f / (w0 * cL[f][q] + w1 * l1);
        ws0[q] = w0 * inv;
        ws1[q] = w1 * inv;
      }
#pragma unroll
      for (int nt = 0; nt < 4; ++nt)
#pragma unroll
        for (int q = 0; q < 4; ++q) {
          int rr = wq * 32 + 16 * f + 4 * lg + q;
          float o1 = ob[rr * 64 + nt * 16 + lr];
          float val = ws0[q] * cO[f][nt][q] + ws1[q] * o1;
          ao[(size_t)(b * SEQ + t0 + rr) * 512 + h * 64 + nt * 16 + lr] = f2bf(val);
        }
    }
  }
}

extern "C" void kernel_launch(void* const* d_in, const int* in_sizes, int n_in,
                              void* d_out, int out_size, void* d_ws, size_t ws_size,
                              hipStream_t stream) {
  const float* x   = (const float*)d_in[0];
  const float* pe  = (const float*)d_in[1];
  const float* Wq  = (const float*)d_in[2];
  const float* bq  = (const float*)d_in[3];
  const float* Wk  = (const float*)d_in[4];
  const float* bk  = (const float*)d_in[5];
  const float* Wv  = (const float*)d_in[6];
  const float* bv  = (const float*)d_in[7];
  const float* Wp  = (const float*)d_in[8];
  const float* bp  = (const float*)d_in[9];
  const float* Wo  = (const float*)d_in[10];
  const float* bo  = (const float*)d_in[11];
  const float* pbu = (const float*)d_in[12];
  const float* pbv = (const float*)d_in[13];

  char* ws = (char*)d_ws;
  size_t o = 0;
  auto alloc = [&](size_t bytes) { size_t r = o; o += (bytes + 255) & ~(size_t)255; return r; };
  u16* x_bf  = (u16*)(ws + alloc((size_t)4096 * 512 * 2));
  u16* pe_bf = (u16*)(ws + alloc((size_t)2048 * 512 * 2));
  u16* wt    = (u16*)(ws + alloc((size_t)5 * 512 * 512 * 2));
  u16* qq    = (u16*)(ws + alloc((size_t)4096 * 512 * 2));
  u16* kk    = (u16*)(ws + alloc((size_t)4096 * 512 * 2));
  u16* vt    = (u16*)(ws + alloc((size_t)4096 * 512 * 2));
  u16* pp    = (u16*)(ws + alloc((size_t)2048 * 512 * 2));
  u16* ao    = (u16*)(ws + alloc((size_t)4096 * 512 * 2));

  dim3 blk(256);
  prep<<<dim3(4352), blk, 0, stream>>>(x, pe, Wq, Wk, Wv, Wp, Wo, x_bf, pe_bf, wt);
  gemm_qkvp<<<dim3(4, 32, 4), blk, 0, stream>>>(x_bf, pe_bf, wt, bq, bk, bv, bp,
                                                qq, kk, vt, pp);
  attn_mfma<<<dim3(8, NHEAD, BATCH), dim3(512), 0, stream>>>(qq, pbu, pbv, kk, vt,
                                                             pp, ao);
  gemm_wo<<<dim3(8, 64), blk, 0, stream>>>(ao, wt, bo, (float*)d_out);
}

// Round 16
// 77.182 us; speedup vs baseline: 1.1655x; 1.1655x over previous
//
#include <hip/hip_runtime.h>
#include <math.h>

#define BATCH 4
#define SEQ   1024
#define HID   512
#define NHEAD 8

typedef unsigned short u16;
typedef unsigned int   u32;
typedef short  short8 __attribute__((ext_vector_type(8)));
typedef float  f32x4  __attribute__((ext_vector_type(4)));

__device__ __forceinline__ u16 f2bf(float x) {
  u32 u = __builtin_bit_cast(u32, x);
  u32 r = (u + 0x7FFFu + ((u >> 16) & 1u)) >> 16;
  return (u16)r;
}

// ---------------- fp32 -> bf16 convert: x (524288 float4s) then pe (262016) --
__global__ __launch_bounds__(256)
void cvt_two(const float* __restrict__ x, const float* __restrict__ pe,
             u16* __restrict__ xb, u16* __restrict__ peb) {
  int i = blockIdx.x * 256 + threadIdx.x;
  const float* s;
  u16* d;
  if (i < 524288) {
    s = x; d = xb;
  } else {
    i -= 524288;
    if (i >= 262016) return;
    s = pe; d = peb;
  }
  float4 v = *(const float4*)&s[(size_t)i * 4];
  ushort4 o;
  o.x = f2bf(v.x); o.y = f2bf(v.y); o.z = f2bf(v.z); o.w = f2bf(v.w);
  *(ushort4*)&d[(size_t)i * 4] = o;
}

// ---------------- W (512x512 f32 k-major) -> Wt (n-major bf16), 5 mats -------
__global__ __launch_bounds__(256)
void transpose_w(const float* w0, const float* w1, const float* w2,
                 const float* w3, const float* w4, u16* __restrict__ wt) {
  const float* src;
  switch (blockIdx.z) {
    case 0: src = w0; break;
    case 1: src = w1; break;
    case 2: src = w2; break;
    case 3: src = w3; break;
    default: src = w4; break;
  }
  u16* dst = wt + (size_t)blockIdx.z * 512 * 512;
  __shared__ float t[32][33];
  const int tx = threadIdx.x, ty = threadIdx.y;  // block (32,8)
  const int k0 = blockIdx.x * 32, n0 = blockIdx.y * 32;
#pragma unroll
  for (int r = 0; r < 4; ++r)
    t[ty + 8 * r][tx] = src[(size_t)(k0 + ty + 8 * r) * 512 + n0 + tx];
  __syncthreads();
#pragma unroll
  for (int r = 0; r < 4; ++r)
    dst[(size_t)(n0 + ty + 8 * r) * 512 + k0 + tx] = f2bf(t[tx][ty + 8 * r]);
}

// ---------------- MFMA GEMM core (serial reg staging — verified) -------------
template <int MF, int NF>
__device__ __forceinline__ void gemm_core(const u16* __restrict__ A,
                                          const u16* __restrict__ Bt,
                                          int m0, int n0, u16* As, u16* Bs,
                                          f32x4 (&acc)[MF][NF]) {
  const int tid = threadIdx.x;
  const int wid = tid >> 6, lane = tid & 63;
  const int lr = lane & 15, lg = lane >> 4;
  const int wm = wid >> 1, wn = wid & 1;
  const int srow = tid >> 3, sc = tid & 7;
#pragma unroll
  for (int i = 0; i < MF; ++i)
#pragma unroll
    for (int j = 0; j < NF; ++j) acc[i][j] = (f32x4)0.f;

  for (int kt = 0; kt < 8; ++kt) {
    const int k0 = kt * 64;
    short8 la[MF], lb[NF];
#pragma unroll
    for (int r = 0; r < MF; ++r)
      la[r] = *(const short8*)&A[(size_t)(m0 + srow + 32 * r) * 512 + k0 + sc * 8];
#pragma unroll
    for (int r = 0; r < NF; ++r)
      lb[r] = *(const short8*)&Bt[(size_t)(n0 + srow + 32 * r) * 512 + k0 + sc * 8];
    __syncthreads();
#pragma unroll
    for (int r = 0; r < MF; ++r) {
      int row = srow + 32 * r;
      *(short8*)&As[row * 64 + ((sc ^ (row & 7)) * 8)] = la[r];
    }
#pragma unroll
    for (int r = 0; r < NF; ++r) {
      int row = srow + 32 * r;
      *(short8*)&Bs[row * 64 + ((sc ^ (row & 7)) * 8)] = lb[r];
    }
    __syncthreads();
#pragma unroll
    for (int kc = 0; kc < 2; ++kc) {
      const int ch = kc * 4 + lg;
      short8 af[MF], bfr[NF];
#pragma unroll
      for (int mt = 0; mt < MF; ++mt) {
        int row = wm * (MF * 16) + mt * 16 + lr;
        af[mt] = *(const short8*)&As[row * 64 + ((ch ^ (row & 7)) * 8)];
      }
#pragma unroll
      for (int nt = 0; nt < NF; ++nt) {
        int row = wn * (NF * 16) + nt * 16 + lr;
        bfr[nt] = *(const short8*)&Bs[row * 64 + ((ch ^ (row & 7)) * 8)];
      }
#pragma unroll
      for (int mt = 0; mt < MF; ++mt)
#pragma unroll
        for (int nt = 0; nt < NF; ++nt)
          acc[mt][nt] = __builtin_amdgcn_mfma_f32_16x16x32_bf16(
              af[mt], bfr[nt], acc[mt][nt], 0, 0, 0);
    }
  }
}

// ---------------- fused Q/K/V/P projection GEMM (z = 0..3) ------------------
__global__ __launch_bounds__(256)
void gemm_qkvp(const u16* __restrict__ xbf, const u16* __restrict__ pebf,
               const u16* __restrict__ wt,
               const float* __restrict__ bq, const float* __restrict__ bk,
               const float* __restrict__ bv, const float* __restrict__ bp,
               const float* __restrict__ pbu, const float* __restrict__ pbv,
               u16* __restrict__ qu, u16* __restrict__ qv,
               u16* __restrict__ kk, u16* __restrict__ vt,
               u16* __restrict__ pp) {
  __shared__ __align__(16) u16 As[128 * 64];
  __shared__ __align__(16) u16 Bs[128 * 64];
  const int z = blockIdx.z;
  if (z == 3 && blockIdx.y >= 16) return;
  const u16* A = (z == 3) ? pebf : xbf;
  const u16* Bt = wt + (size_t)z * 512 * 512;
  const float* bias = (z == 0) ? bq : (z == 1) ? bk : (z == 2) ? bv : bp;
  const int m0 = blockIdx.y * 128, n0 = blockIdx.x * 128;

  f32x4 acc[4][4];
  gemm_core<4, 4>(A, Bt, m0, n0, As, Bs, acc);

  const int tid = threadIdx.x, wid = tid >> 6, lane = tid & 63;
  const int lr = lane & 15, lg = lane >> 4, wm = wid >> 1, wn = wid & 1;
#pragma unroll
  for (int mt = 0; mt < 4; ++mt)
#pragma unroll
    for (int nt = 0; nt < 4; ++nt) {
      const int col = n0 + wn * 64 + nt * 16 + lr;
      const int rb = m0 + wm * 64 + mt * 16 + lg * 4;
      const float bcol = bias[col];
      if (z == 0) {
        const float uu = pbu[col], vv = pbv[col];
#pragma unroll
        for (int q = 0; q < 4; ++q) {
          float val = acc[mt][nt][q] + bcol;
          qu[(size_t)(rb + q) * 512 + col] = f2bf(val + uu);
          qv[(size_t)(rb + q) * 512 + col] = f2bf(val + vv);
        }
      } else if (z == 1) {
#pragma unroll
        for (int q = 0; q < 4; ++q)
          kk[(size_t)(rb + q) * 512 + col] = f2bf(acc[mt][nt][q] + bcol);
      } else if (z == 2) {
        // V^T layout [b][h][d][t]
        ushort4 pk;
        pk.x = f2bf(acc[mt][nt][0] + bcol);
        pk.y = f2bf(acc[mt][nt][1] + bcol);
        pk.z = f2bf(acc[mt][nt][2] + bcol);
        pk.w = f2bf(acc[mt][nt][3] + bcol);
        int bb = rb >> 10, tl = rb & 1023;
        *(ushort4*)&vt[(size_t)((bb * 8 + (col >> 6)) * 64 + (col & 63)) * 1024 + tl] = pk;
      } else {
#pragma unroll
        for (int q = 0; q < 4; ++q)
          if (rb + q < 2047)
            pp[(size_t)(rb + q) * 512 + col] = f2bf(acc[mt][nt][q] + bcol);
      }
    }
}

// ---------------- output projection: out = ao @ Wo^T + bo (f32) -------------
__global__ __launch_bounds__(256)
void gemm_wo(const u16* __restrict__ ao, const u16* __restrict__ wt,
             const float* __restrict__ bo, float* __restrict__ out) {
  __shared__ __align__(16) u16 As[64 * 64];
  __shared__ __align__(16) u16 Bs[64 * 64];
  const int m0 = blockIdx.y * 64, n0 = blockIdx.x * 64;
  f32x4 acc[2][2];
  gemm_core<2, 2>(ao, wt + (size_t)4 * 512 * 512, m0, n0, As, Bs, acc);
  const int tid = threadIdx.x, wid = tid >> 6, lane = tid & 63;
  const int lr = lane & 15, lg = lane >> 4, wm = wid >> 1, wn = wid & 1;
#pragma unroll
  for (int mt = 0; mt < 2; ++mt)
#pragma unroll
    for (int nt = 0; nt < 2; ++nt) {
      const int col = n0 + wn * 32 + nt * 16 + lr;
      const int rb = m0 + wm * 32 + mt * 16 + lg * 4;
      const float bcol = bo[col];
#pragma unroll
      for (int q = 0; q < 4; ++q)
        out[(size_t)(rb + q) * 512 + col] = acc[mt][nt][q] + bcol;
    }
}

// ---------------- flash rel-pos attention, bf16 MFMA, transposed scores ------
// Session-best configuration (round 9, 76.5 us total).
__global__ __launch_bounds__(512)
void attn_mfma(const u16* __restrict__ quP, const u16* __restrict__ qvP,
               const u16* __restrict__ kP, const u16* __restrict__ vtP,
               const u16* __restrict__ pP, u16* __restrict__ ao) {
  // layout (u16 units): Ks[2] @0, Vs[2] @8192, Ps @16384, Wb @32768 (f32)
  __shared__ __align__(16) u16 SM[56832];
  u16* Ps = SM + 16384;

  const int tid = threadIdx.x;
  const int wid = tid >> 6, lane = tid & 63;
  const int lr = lane & 15, lg = lane >> 4;
  const int grp = wid >> 2, wq = wid & 3;
  const int t0 = blockIdx.x * 128, h = blockIdx.y, b = blockIdx.z;
  const int base0 = 896 - t0;  // P ring pos 0 <-> rel index base0

  u16* Ksg = SM + grp * 4096;
  u16* Vsg = SM + 8192 + grp * 4096;
  float* wbf = (float*)(SM + 32768) + wid * 1504;  // Bds_t [16][84] / Es overlay
  u16* esw = (u16*)wbf;

  short8 aqu[2][2], aqv[2][2];
#pragma unroll
  for (int f = 0; f < 2; ++f)
#pragma unroll
    for (int kc = 0; kc < 2; ++kc) {
      size_t g = (size_t)(b * SEQ + t0 + 32 * wq + 16 * f + lr) * 512 + h * 64 +
                 kc * 32 + lg * 8;
      aqu[f][kc] = *(const short8*)&quP[g];
      aqv[f][kc] = *(const short8*)&qvP[g];
    }
  short8 ones;
#pragma unroll
  for (int i = 0; i < 8; ++i) ones[i] = (short)0x3F80;  // bf16 1.0

  float mrun[2] = {-1e30f, -1e30f};  // per-lane running max (t = lr)
  f32x4 cL[2], cO[2][4];
#pragma unroll
  for (int f = 0; f < 2; ++f) {
    cL[f] = (f32x4)0.f;
#pragma unroll
    for (int nt = 0; nt < 4; ++nt) cO[f][nt] = (f32x4)0.f;
  }

  // ---- prologue staging: K/V j-rows 0..127, P ring rel base0..base0+255 ----
#pragma unroll
  for (int r = 0; r < 2; ++r) {
    int idx = tid + 512 * r;
    int row = idx >> 3, sc = idx & 7;
    short8 lk = *(const short8*)&kP[(size_t)(b * SEQ + row) * 512 + h * 64 + sc * 8];
    short8 lv = *(const short8*)&vtP[(size_t)((b * 8 + h) * 64 + (row & 63)) * 1024 +
                                     (row >> 6) * 64 + sc * 8];
    *(short8*)&SM[(row >> 6) * 4096 + (row & 63) * 64 + ((sc ^ (row & 7)) * 8)] = lk;
    *(short8*)&SM[8192 + (row >> 6) * 4096 + (row & 63) * 64 + ((sc ^ (row & 7)) * 8)] = lv;
  }
#pragma unroll
  for (int r = 0; r < 4; ++r) {
    int idx = tid + 512 * r;
    int prow = idx >> 3, sc = idx & 7;  // 0..255
    short8 lp = *(const short8*)&pP[(size_t)(base0 + prow) * 512 + h * 64 + sc * 8];
    *(short8*)&Ps[prow * 64 + ((sc ^ (prow & 7)) * 8)] = lp;
  }
  __syncthreads();

  for (int s = 0; s < 8; ++s) {
    // ---- T14: issue next superstep's global loads early ----
    short8 nk[2], nv[2], np[2];
    if (s < 7) {
      const int jn = 128 * (s + 1);
#pragma unroll
      for (int r = 0; r < 2; ++r) {
        int idx = tid + 512 * r;
        int row = idx >> 3, sc = idx & 7;
        nk[r] = *(const short8*)&kP[(size_t)(b * SEQ + jn + row) * 512 + h * 64 + sc * 8];
        nv[r] = *(const short8*)&vtP[(size_t)((b * 8 + h) * 64 + (row & 63)) * 1024 +
                                     jn + (row >> 6) * 64 + sc * 8];
        np[r] = *(const short8*)&pP[(size_t)(base0 + 256 + 128 * s + row) * 512 +
                                    h * 64 + sc * 8];
      }
    }

    // ---- S^T = mfma(A=K, B=Qu): row=j(lg*4+q+16nt), col=t(lr) ----
    f32x4 cKT[2][4];
#pragma unroll
    for (int f = 0; f < 2; ++f)
#pragma unroll
      for (int nt = 0; nt < 4; ++nt) cKT[f][nt] = (f32x4)0.f;
    __builtin_amdgcn_s_setprio(1);
#pragma unroll
    for (int kc = 0; kc < 2; ++kc) {
      const int ch = kc * 4 + lg;
#pragma unroll
      for (int nt = 0; nt < 4; ++nt) {
        int krow = nt * 16 + lr;
        short8 bk = *(const short8*)&Ksg[krow * 64 + ((ch ^ (krow & 7)) * 8)];
        cKT[0][nt] = __builtin_amdgcn_mfma_f32_16x16x32_bf16(bk, aqu[0][kc], cKT[0][nt], 0, 0, 0);
        cKT[1][nt] = __builtin_amdgcn_mfma_f32_16x16x32_bf16(bk, aqu[1][kc], cKT[1][nt], 0, 0, 0);
      }
    }
    __builtin_amdgcn_s_setprio(0);

    // ---- hoist V fragments (each feeds both f's PV) ----
    short8 bvr[2][4];
#pragma unroll
    for (int kc = 0; kc < 2; ++kc) {
      const int ch = kc * 4 + lg;
#pragma unroll
      for (int nt = 0; nt < 4; ++nt) {
        int vr = nt * 16 + lr;
        bvr[kc][nt] = *(const short8*)&Vsg[vr * 64 + ((ch ^ (vr & 7)) * 8)];
      }
    }

#pragma unroll
    for (int f = 0; f < 2; ++f) {
      // window: ring pos = (poff + w) & 255, w = winpos 0..79
      const int poff = 112 - 32 * wq - 16 * f + 64 * grp + 128 * s;
      // cP^T = mfma(A=P, B=Qv): row = w (lg*4+q+16pt), col = t (lr)
      f32x4 cPT[5];
#pragma unroll
      for (int i = 0; i < 5; ++i) cPT[i] = (f32x4)0.f;
      __builtin_amdgcn_s_setprio(1);
#pragma unroll
      for (int kc = 0; kc < 2; ++kc) {
        const int ch = kc * 4 + lg;
        const int swz = (ch ^ (lr & 7)) * 8;  // pos & 7 == lr & 7
#pragma unroll
        for (int pt = 0; pt < 5; ++pt) {
          int pos = (poff + pt * 16 + lr) & 255;
          short8 bp = *(const short8*)&Ps[pos * 64 + swz];
          cPT[pt] = __builtin_amdgcn_mfma_f32_16x16x32_bf16(bp, aqv[f][kc], cPT[pt], 0, 0, 0);
        }
      }
      __builtin_amdgcn_s_setprio(0);

      // ---- Bds_t [t=lr][w:84]: b128 writes (4 q-consecutive w per reg) ----
#pragma unroll
      for (int pt = 0; pt < 5; ++pt)
        *(f32x4*)&wbf[lr * 84 + pt * 16 + lg * 4] = cPT[pt];
      // read shifted: w = j + 15 - t_local = 16nt + lg*4 + q + 15 - lr
      float sv[4][4];
#pragma unroll
      for (int nt = 0; nt < 4; ++nt)
#pragma unroll
        for (int q = 0; q < 4; ++q)
          sv[nt][q] = 0.125f * (cKT[f][nt][q] +
                                wbf[lr * 84 + 16 * nt + lg * 4 + q + 15 - lr]);

      // ---- per-lane softmax (t = lr): in-reg max + 2 cross-lane ----
      float tm = sv[0][0];
#pragma unroll
      for (int nt = 0; nt < 4; ++nt)
#pragma unroll
        for (int q = 0; q < 4; ++q) tm = fmaxf(tm, sv[nt][q]);
      tm = fmaxf(tm, __shfl_xor(tm, 16));
      tm = fmaxf(tm, __shfl_xor(tm, 32));
      // defer-max (THR=8)
      if (__any(tm > mrun[f] + 8.f)) {
        float mnew = fmaxf(mrun[f], tm);
        float corr = __expf(mrun[f] - mnew);
        mrun[f] = mnew;
        // corr lives at t=lr; C rows are t=lg*4+q -> transpose via shfl (rare)
        float cc[4];
#pragma unroll
        for (int q = 0; q < 4; ++q)
          cc[q] = __shfl(corr, (lane & 48) | (lg * 4 + q));
#pragma unroll
        for (int q = 0; q < 4; ++q) {
          cL[f][q] *= cc[q];
#pragma unroll
          for (int nt = 0; nt < 4; ++nt) cO[f][nt][q] *= cc[q];
        }
      }

      // ---- exp -> bf16 -> Es_T: 4 swizzled b64 writes (j lane-local) ----
#pragma unroll
      for (int nt = 0; nt < 4; ++nt) {
        float e0 = __expf(sv[nt][0] - mrun[f]);
        float e1 = __expf(sv[nt][1] - mrun[f]);
        float e2 = __expf(sv[nt][2] - mrun[f]);
        float e3 = __expf(sv[nt][3] - mrun[f]);
        uint2 pk;
        pk.x = (u32)f2bf(e0) | ((u32)f2bf(e1) << 16);
        pk.y = (u32)f2bf(e2) | ((u32)f2bf(e3) << 16);
        int g = 2 * nt + (lg >> 1);  // j-granule (8 u16)
        *(uint2*)&esw[lr * 64 + ((g ^ (lr & 7)) * 8) + (lg & 1) * 4] = pk;
      }

      // ---- PV + denominator: pa = E A-frag (row=t=lr, k=j) ----
      __builtin_amdgcn_s_setprio(1);
#pragma unroll
      for (int kc = 0; kc < 2; ++kc) {
        const int ch = kc * 4 + lg;
        short8 pa = *(const short8*)&esw[lr * 64 + ((ch ^ (lr & 7)) * 8)];
        cL[f] = __builtin_amdgcn_mfma_f32_16x16x32_bf16(pa, ones, cL[f], 0, 0, 0);
#pragma unroll
        for (int nt = 0; nt < 4; ++nt)
          cO[f][nt] = __builtin_amdgcn_mfma_f32_16x16x32_bf16(pa, bvr[kc][nt], cO[f][nt], 0, 0, 0);
      }
      __builtin_amdgcn_s_setprio(0);
    }

    __syncthreads();
    // ---- write staged tiles for next superstep ----
    if (s < 7) {
#pragma unroll
      for (int r = 0; r < 2; ++r) {
        int idx = tid + 512 * r;
        int row = idx >> 3, sc = idx & 7;
        *(short8*)&SM[(row >> 6) * 4096 + (row & 63) * 64 + ((sc ^ (row & 7)) * 8)] = nk[r];
        *(short8*)&SM[8192 + (row >> 6) * 4096 + (row & 63) * 64 + ((sc ^ (row & 7)) * 8)] = nv[r];
        int pos = (128 * s + row) & 255;
        *(short8*)&Ps[pos * 64 + ((sc ^ (pos & 7)) * 8)] = np[r];
      }
    }
    __syncthreads();
  }

  // ---- transpose m to C-layout rows (once) ----
  float m_c[2][4];
#pragma unroll
  for (int f = 0; f < 2; ++f)
#pragma unroll
    for (int q = 0; q < 4; ++q)
      m_c[f][q] = __shfl(mrun[f], (lane & 48) | (lg * 4 + q));

  // ---- merge j-halves (exact flash merge) via LDS overlay ----
  float* ob = (float*)SM;             // 128 x 64 f32 (Ks+Vs region)
  float* mlb = (float*)(SM + 16384);  // 128 x {m,l} (Ps region)
  if (grp == 1) {
#pragma unroll
    for (int f = 0; f < 2; ++f) {
#pragma unroll
      for (int nt = 0; nt < 4; ++nt)
#pragma unroll
        for (int q = 0; q < 4; ++q)
          ob[(wq * 32 + 16 * f + 4 * lg + q) * 64 + nt * 16 + lr] = cO[f][nt][q];
      if (lr == 0) {
#pragma unroll
        for (int q = 0; q < 4; ++q) {
          int rr = wq * 32 + 16 * f + 4 * lg + q;
          mlb[rr * 2 + 0] = m_c[f][q];
          mlb[rr * 2 + 1] = cL[f][q];
        }
      }
    }
  }
  __syncthreads();
  if (grp == 0) {
#pragma unroll
    for (int f = 0; f < 2; ++f) {
      float ws0[4], ws1[4];
#pragma unroll
      for (int q = 0; q < 4; ++q) {
        int rr = wq * 32 + 16 * f + 4 * lg + q;
        float m1 = mlb[rr * 2 + 0], l1 = mlb[rr * 2 + 1];
        float M = fmaxf(m_c[f][q], m1);
        float w0 = __expf(m_c[f][q] - M), w1 = __expf(m1 - M);
        float inv = 1.f / (w0 * cL[f][q] + w1 * l1);
        ws0[q] = w0 * inv;
        ws1[q] = w1 * inv;
      }
#pragma unroll
      for (int nt = 0; nt < 4; ++nt)
#pragma unroll
        for (int q = 0; q < 4; ++q) {
          int rr = wq * 32 + 16 * f + 4 * lg + q;
          float o1 = ob[rr * 64 + nt * 16 + lr];
          float val = ws0[q] * cO[f][nt][q] + ws1[q] * o1;
          ao[(size_t)(b * SEQ + t0 + rr) * 512 + h * 64 + nt * 16 + lr] = f2bf(val);
        }
    }
  }
}

extern "C" void kernel_launch(void* const* d_in, const int* in_sizes, int n_in,
                              void* d_out, int out_size, void* d_ws, size_t ws_size,
                              hipStream_t stream) {
  const float* x   = (const float*)d_in[0];
  const float* pe  = (const float*)d_in[1];
  const float* Wq  = (const float*)d_in[2];
  const float* bq  = (const float*)d_in[3];
  const float* Wk  = (const float*)d_in[4];
  const float* bk  = (const float*)d_in[5];
  const float* Wv  = (const float*)d_in[6];
  const float* bv  = (const float*)d_in[7];
  const float* Wp  = (const float*)d_in[8];
  const float* bp  = (const float*)d_in[9];
  const float* Wo  = (const float*)d_in[10];
  const float* bo  = (const float*)d_in[11];
  const float* pbu = (const float*)d_in[12];
  const float* pbv = (const float*)d_in[13];

  char* ws = (char*)d_ws;
  size_t o = 0;
  auto alloc = [&](size_t bytes) { size_t r = o; o += (bytes + 255) & ~(size_t)255; return r; };
  u16* x_bf  = (u16*)(ws + alloc((size_t)4096 * 512 * 2));
  u16* pe_bf = (u16*)(ws + alloc((size_t)2048 * 512 * 2));
  u16* wt    = (u16*)(ws + alloc((size_t)5 * 512 * 512 * 2));
  u16* qu    = (u16*)(ws + alloc((size_t)4096 * 512 * 2));
  u16* qv    = (u16*)(ws + alloc((size_t)4096 * 512 * 2));
  u16* kk    = (u16*)(ws + alloc((size_t)4096 * 512 * 2));
  u16* vt    = (u16*)(ws + alloc((size_t)4096 * 512 * 2));
  u16* pp    = (u16*)(ws + alloc((size_t)2048 * 512 * 2));
  u16* ao    = (u16*)(ws + alloc((size_t)4096 * 512 * 2));

  dim3 blk(256);
  cvt_two<<<dim3(3072), blk, 0, stream>>>(x, pe, x_bf, pe_bf);
  transpose_w<<<dim3(16, 16, 5), dim3(32, 8), 0, stream>>>(Wq, Wk, Wv, Wp, Wo, wt);
  hipMemsetAsync(pp + (size_t)2047 * 512, 0, 512 * 2, stream);

  gemm_qkvp<<<dim3(4, 32, 4), blk, 0, stream>>>(x_bf, pe_bf, wt, bq, bk, bv, bp,
                                                pbu, pbv, qu, qv, kk, vt, pp);
  attn_mfma<<<dim3(8, NHEAD, BATCH), dim3(512), 0, stream>>>(qu, qv, kk, vt, pp, ao);
  gemm_wo<<<dim3(8, 64), blk, 0, stream>>>(ao, wt, bo, (float*)d_out);
}